// Round 1
// baseline (894.153 us; speedup 1.0000x reference)
//
#include <hip/hip_runtime.h>
#include <hip/hip_bf16.h>

// Problem constants (VID tube linking)
#define T_WIN 16
#define RR    512
#define DD    4096
#define NCLS  31
#define NBB   124          // 4*NCLS
#define NPAIR 15           // T_WIN-1
#define NOUT  (T_WIN*RR)   // 8192
#define NHEAD (NCLS+NBB)   // 155

// Workspace layout (bytes). Total ~2.6 MB.
#define OFF_NORMS 0u        // f32[8192]
#define OFF_KEYS  32768u    // u64[15*512]
#define OFF_IDX   94208u    // i32[15*512]
#define OFF_SRC   124928u   // i32[512]
#define OFF_LBL   126976u   // i32[512]
#define OFF_NCMP  129024u   // i32[1]
#define OFF_WT    131072u   // f32[155*4096]

// ---------------------------------------------------------------------------
// Prep: zero the packed max-keys (ws is poisoned 0xAA each launch) and build
// Wt = [W_cls | W_bbox]^T as [155][4096] so head dot-products read contiguous.
__global__ __launch_bounds__(256) void k_prep(unsigned long long* __restrict__ keys,
                                              const float* __restrict__ Wc,
                                              const float* __restrict__ Wb,
                                              float* __restrict__ Wt) {
    int i = blockIdx.x * 256 + threadIdx.x;
    if (i < NPAIR * RR) keys[i] = 0ull;
    if (i < NHEAD * DD) {
        int d = i & (DD - 1);
        int o = i >> 12;                       // DD = 4096 = 2^12
        Wt[i] = (o < NCLS) ? Wc[d * NCLS + o] : Wb[d * NBB + (o - NCLS)];
    }
}

// ---------------------------------------------------------------------------
// Row squared-norms of pooled_feat: norms[t*R+i] = sum_d f^2
__global__ __launch_bounds__(256) void k_norms(const float* __restrict__ pf,
                                               float* __restrict__ norms) {
    int row = blockIdx.x;                      // 0..8191
    const float* p = pf + (size_t)row * DD;
    int tid = threadIdx.x;
    float s = 0.f;
    for (int d = tid * 4; d < DD; d += 1024) {
        float4 v = *(const float4*)(p + d);
        s = fmaf(v.x, v.x, s); s = fmaf(v.y, v.y, s);
        s = fmaf(v.z, v.z, s); s = fmaf(v.w, v.w, s);
    }
    for (int off = 32; off; off >>= 1) s += __shfl_down(s, off);
    __shared__ float wsum[4];
    int wid = tid >> 6, lane = tid & 63;
    if (lane == 0) wsum[wid] = s;
    __syncthreads();
    if (tid == 0) norms[row] = wsum[0] + wsum[1] + wsum[2] + wsum[3];
}

// ---------------------------------------------------------------------------
// Pair matching: for pair t, 64x64 tile of C[i][j] = fa_i . fb_j, then
// metric = IoU(ra_i, rb_j) + 1/(1+sqrt(max(|a|^2+|b|^2-2ab, 0))), column-max
// (over i) reduced via packed u64 atomicMax (tie-break = smallest i).
__global__ __launch_bounds__(256) void k_match(const float* __restrict__ pf,
                                               const float* __restrict__ rois,
                                               const float* __restrict__ norms,
                                               unsigned long long* __restrict__ keys) {
    const int t  = blockIdx.z;            // pair index, frames (t, t+1)
    const int ib = blockIdx.y * 64;       // first-frame rows
    const int jb = blockIdx.x * 64;       // second-frame rows
    const float* fa = pf + (size_t)t * RR * DD;
    const float* fb = pf + (size_t)(t + 1) * RR * DD;

    __shared__ float As[32][68];          // [k][i], padded stride
    __shared__ float Bs[32][68];          // [k][j]
    __shared__ float4 ra4[64];
    __shared__ float4 rb4[64];
    __shared__ unsigned long long red[16][64];

    const int tid = threadIdx.x;
    const int tx = tid & 15;              // j micro-tile
    const int ty = tid >> 4;              // i micro-tile

    if (tid < 64) {
        ra4[tid] = *(const float4*)(rois + ((size_t)t * RR + ib + tid) * 4);
        rb4[tid] = *(const float4*)(rois + ((size_t)(t + 1) * RR + jb + tid) * 4);
    }

    float acc[4][4];
#pragma unroll
    for (int u = 0; u < 4; ++u)
#pragma unroll
        for (int v = 0; v < 4; ++v) acc[u][v] = 0.f;

    const int lr = tid >> 3;              // 0..31  (tile row)
    const int lk = (tid & 7) * 4;         // 0..28  (k offset)

    for (int k0 = 0; k0 < DD; k0 += 32) {
        float4 a0 = *(const float4*)(fa + (size_t)(ib + lr) * DD + k0 + lk);
        float4 a1 = *(const float4*)(fa + (size_t)(ib + lr + 32) * DD + k0 + lk);
        float4 b0 = *(const float4*)(fb + (size_t)(jb + lr) * DD + k0 + lk);
        float4 b1 = *(const float4*)(fb + (size_t)(jb + lr + 32) * DD + k0 + lk);
        __syncthreads();   // previous tile fully consumed
        As[lk + 0][lr] = a0.x; As[lk + 1][lr] = a0.y; As[lk + 2][lr] = a0.z; As[lk + 3][lr] = a0.w;
        As[lk + 0][lr + 32] = a1.x; As[lk + 1][lr + 32] = a1.y; As[lk + 2][lr + 32] = a1.z; As[lk + 3][lr + 32] = a1.w;
        Bs[lk + 0][lr] = b0.x; Bs[lk + 1][lr] = b0.y; Bs[lk + 2][lr] = b0.z; Bs[lk + 3][lr] = b0.w;
        Bs[lk + 0][lr + 32] = b1.x; Bs[lk + 1][lr + 32] = b1.y; Bs[lk + 2][lr + 32] = b1.z; Bs[lk + 3][lr + 32] = b1.w;
        __syncthreads();
#pragma unroll
        for (int kk = 0; kk < 32; ++kk) {
            float4 av = *(const float4*)&As[kk][ty * 4];
            float4 bv = *(const float4*)&Bs[kk][tx * 4];
            float a_[4] = {av.x, av.y, av.z, av.w};
            float b_[4] = {bv.x, bv.y, bv.z, bv.w};
#pragma unroll
            for (int u = 0; u < 4; ++u)
#pragma unroll
                for (int v = 0; v < 4; ++v)
                    acc[u][v] = fmaf(a_[u], b_[v], acc[u][v]);
        }
    }
    __syncthreads();

    float na[4], nb_[4];
#pragma unroll
    for (int u = 0; u < 4; ++u) na[u]  = norms[t * RR + ib + ty * 4 + u];
#pragma unroll
    for (int v = 0; v < 4; ++v) nb_[v] = norms[(t + 1) * RR + jb + tx * 4 + v];

#pragma unroll
    for (int v = 0; v < 4; ++v) {
        unsigned long long bestkey = 0ull;
        float4 B = rb4[tx * 4 + v];
        float area_b = (B.z - B.x + 1.f) * (B.w - B.y + 1.f);
#pragma unroll
        for (int u = 0; u < 4; ++u) {
            float d2 = fmaxf(na[u] + nb_[v] - 2.f * acc[u][v], 0.f);
            float drev = 1.f / (1.f + sqrtf(d2));
            float4 A = ra4[ty * 4 + u];
            float area_a = (A.z - A.x + 1.f) * (A.w - A.y + 1.f);
            float iw = fmaxf(fminf(A.z, B.z) - fmaxf(A.x, B.x) + 1.f, 0.f);
            float ih = fmaxf(fminf(A.w, B.w) - fmaxf(A.y, B.y) + 1.f, 0.f);
            float inter = iw * ih;
            float iou = inter / (area_a + area_b - inter);
            float m = iou + drev;                              // metric > 0
            int gi = ib + ty * 4 + u;
            unsigned long long key =
                ((unsigned long long)__float_as_uint(m) << 32) |
                (unsigned long long)(unsigned)(RR - 1 - gi);   // ties -> smaller i
            if (key > bestkey) bestkey = key;
        }
        red[ty][tx * 4 + v] = bestkey;
    }
    __syncthreads();
    if (tid < 64) {
        unsigned long long best = red[0][tid];
#pragma unroll
        for (int r = 1; r < 16; ++r) {
            unsigned long long k = red[r][tid];
            if (k > best) best = k;
        }
        atomicMax(&keys[(size_t)t * RR + jb + tid], best);
    }
}

// ---------------------------------------------------------------------------
// Finalize: decode keys -> (val, idx); complete = all vals >= 1.0; scan for
// compaction; tube labels. Single block of 512 threads.
__global__ __launch_bounds__(512) void k_finalize(const unsigned long long* __restrict__ keys,
                                                  const int* __restrict__ rlabel,
                                                  int* __restrict__ idx_all,
                                                  int* __restrict__ src,
                                                  int* __restrict__ lblS,
                                                  int* __restrict__ ncomp) {
    __shared__ int sc[RR];
    int j = threadIdx.x;
    bool comp = true;
#pragma unroll
    for (int t = 0; t < NPAIR; ++t) {
        unsigned long long k = keys[t * RR + j];
        float v = __uint_as_float((unsigned)(k >> 32));
        idx_all[t * RR + j] = (RR - 1) - (int)(k & 0xffffffffu);
        comp = comp && (v >= 1.0f);   // THR = 1.0
    }
    sc[j] = comp ? 1 : 0;
    __syncthreads();
    for (int off = 1; off < RR; off <<= 1) {
        int v = sc[j];
        int a = (j >= off) ? sc[j - off] : 0;
        __syncthreads();
        sc[j] = v + a;
        __syncthreads();
    }
    if (comp) {
        int pos = sc[j] - 1;
        src[pos] = j;
        int s = 0;
#pragma unroll
        for (int t = 0; t < T_WIN; ++t) s += rlabel[t * RR + j];
        int ref = rlabel[j];
        lblS[pos] = ((s / T_WIN) == ref) ? ref : 0;
    }
    if (j == RR - 1) *ncomp = sc[RR - 1];
}

// ---------------------------------------------------------------------------
// Heads: one block per output row. Live rows (r < ncomp) gather+sum the tube
// feature then dot with Wt; dead rows emit softmax(b_cls), b_bbox, 0.
__global__ __launch_bounds__(256) void k_heads(const float* __restrict__ pf,
                                               const float* __restrict__ Wt,
                                               const float* __restrict__ bc,
                                               const float* __restrict__ bbias,
                                               const int* __restrict__ src,
                                               const int* __restrict__ lblS,
                                               const int* __restrict__ ncompp,
                                               const int* __restrict__ idx_all,
                                               float* __restrict__ out) {
    __shared__ float feat[DD];
    __shared__ float scores[NHEAD];
    __shared__ int ridx[NPAIR];
    __shared__ float mx, sm;

    int r = blockIdx.x;
    int tid = threadIdx.x;
    int ncomp = *ncompp;
    bool comp = (r < ncomp);           // uniform per block

    if (comp) {
        int j = src[r];
        if (tid < NPAIR) ridx[tid] = idx_all[tid * RR + j];
        __syncthreads();
        for (int d = tid * 4; d < DD; d += 1024) {
            float4 s = *(const float4*)(pf + (size_t)j * DD + d);   // frame 0
#pragma unroll
            for (int t = 0; t < NPAIR; ++t) {
                float4 g = *(const float4*)(pf + ((size_t)(t + 1) * RR + ridx[t]) * DD + d);
                s.x += g.x; s.y += g.y; s.z += g.z; s.w += g.w;
            }
            *(float4*)&feat[d] = s;
        }
        __syncthreads();
        int wid = tid >> 6, lane = tid & 63;
        for (int o = wid; o < NHEAD; o += 4) {
            const float* w = Wt + (size_t)o * DD;
            float s = 0.f;
            for (int d = lane * 4; d < DD; d += 256) {
                float4 wv = *(const float4*)(w + d);
                float4 fv = *(const float4*)&feat[d];
                s = fmaf(wv.x, fv.x, s); s = fmaf(wv.y, fv.y, s);
                s = fmaf(wv.z, fv.z, s); s = fmaf(wv.w, fv.w, s);
            }
            for (int off = 32; off; off >>= 1) s += __shfl_down(s, off);
            if (lane == 0) scores[o] = s + (o < NCLS ? bc[o] : bbias[o - NCLS]);
        }
        __syncthreads();
    } else {
        if (tid < NHEAD) scores[tid] = (tid < NCLS ? bc[tid] : bbias[tid - NCLS]);
        __syncthreads();
    }

    if (tid == 0) {
        float m = scores[0];
        for (int c = 1; c < NCLS; ++c) m = fmaxf(m, scores[c]);
        float s = 0.f;
        for (int c = 0; c < NCLS; ++c) s += expf(scores[c] - m);
        mx = m; sm = s;
    }
    __syncthreads();

    float* cls = out;                                   // [NOUT][NCLS]
    float* bb  = out + (size_t)NOUT * NCLS;             // [NOUT][NBB]
    float* lb  = out + (size_t)NOUT * (NCLS + NBB);     // [NOUT]
    if (tid < NCLS) cls[(size_t)r * NCLS + tid] = expf(scores[tid] - mx) / sm;
    if (tid < NBB)  bb[(size_t)r * NBB + tid]   = scores[NCLS + tid];
    if (tid == 0)   lb[r] = comp ? (float)lblS[r] : 0.f;
}

// ---------------------------------------------------------------------------
extern "C" void kernel_launch(void* const* d_in, const int* in_sizes, int n_in,
                              void* d_out, int out_size, void* d_ws, size_t ws_size,
                              hipStream_t stream) {
    (void)in_sizes; (void)n_in; (void)out_size; (void)ws_size;
    const float* pf   = (const float*)d_in[0];
    const float* rois = (const float*)d_in[1];
    const int*   rlab = (const int*)d_in[2];
    const float* Wc   = (const float*)d_in[3];
    const float* bc   = (const float*)d_in[4];
    const float* Wb   = (const float*)d_in[5];
    const float* bbv  = (const float*)d_in[6];

    char* ws = (char*)d_ws;
    float*              norms   = (float*)(ws + OFF_NORMS);
    unsigned long long* keys    = (unsigned long long*)(ws + OFF_KEYS);
    int*                idx_all = (int*)(ws + OFF_IDX);
    int*                src     = (int*)(ws + OFF_SRC);
    int*                lblS    = (int*)(ws + OFF_LBL);
    int*                ncomp   = (int*)(ws + OFF_NCMP);
    float*              Wt      = (float*)(ws + OFF_WT);
    float*              out     = (float*)d_out;

    k_prep<<<dim3(2480), dim3(256), 0, stream>>>(keys, Wc, Wb, Wt);
    k_norms<<<dim3(T_WIN * RR), dim3(256), 0, stream>>>(pf, norms);
    k_match<<<dim3(8, 8, NPAIR), dim3(256), 0, stream>>>(pf, rois, norms, keys);
    k_finalize<<<dim3(1), dim3(512), 0, stream>>>(keys, rlab, idx_all, src, lblS, ncomp);
    k_heads<<<dim3(NOUT), dim3(256), 0, stream>>>(pf, Wt, bc, bbv, src, lblS, ncomp, idx_all, out);
}

// Round 6
// 746.999 us; speedup vs baseline: 1.1970x; 1.1970x over previous
//
#include <hip/hip_runtime.h>
#include <hip/hip_bf16.h>

// Problem constants (VID tube linking)
#define T_WIN 16
#define RR    512
#define DD    4096
#define NCLS  31
#define NBB   124          // 4*NCLS
#define NPAIR 15           // T_WIN-1
#define NOUT  (T_WIN*RR)   // 8192
#define NHEAD (NCLS+NBB)   // 155

// Workspace layout (bytes).
#define OFF_NORMS 0u          // f32[8192]
#define OFF_KEYS  32768u      // u64[15*512]
#define OFF_IDX   98304u      // i32[15*512]
#define OFF_SRC   131072u     // i32[512]
#define OFF_LBL   135168u     // i32[512]
#define OFF_NCMP  139264u     // i32[1]
#define OFF_WT    262144u     // f32[155*4096]
#define OFF_PH    4194304u    // bf16[8192*4096]  (hi)
#define OFF_PL    71303168u   // bf16[8192*4096]  (lo)
#define WS_NEED   138412032u

typedef __bf16 bf16x8 __attribute__((ext_vector_type(8)));
typedef float  f32x4  __attribute__((ext_vector_type(4)));

__device__ __forceinline__ unsigned short f2bf(float f) {
    unsigned u = __float_as_uint(f);
    unsigned r = (u + 0x7fffu + ((u >> 16) & 1u)) >> 16;   // RNE
    return (unsigned short)r;
}
__device__ __forceinline__ float bf2f(unsigned short h) {
    return __uint_as_float(((unsigned)h) << 16);
}
__device__ __forceinline__ unsigned long long u64max(unsigned long long a, unsigned long long b) {
    return a > b ? a : b;
}

// ---------------------------------------------------------------------------
// Prep: zero packed max-keys; build Wt = [W_cls | W_bbox]^T as [155][4096].
__global__ __launch_bounds__(256) void k_prep(unsigned long long* __restrict__ keys,
                                              const float* __restrict__ Wc,
                                              const float* __restrict__ Wb,
                                              float* __restrict__ Wt) {
    int i = blockIdx.x * 256 + threadIdx.x;
    if (i < NPAIR * RR) keys[i] = 0ull;
    if (i < NHEAD * DD) {
        int d = i & (DD - 1);
        int o = i >> 12;                       // DD = 4096 = 2^12
        Wt[i] = (o < NCLS) ? Wc[d * NCLS + o] : Wb[d * NBB + (o - NCLS)];
    }
}

// ---------------------------------------------------------------------------
// Split f32 -> (hi,lo) bf16 + fused row squared-norms. One block per row.
__global__ __launch_bounds__(256) void k_split(const float* __restrict__ pf,
                                               unsigned short* __restrict__ ph,
                                               unsigned short* __restrict__ pl,
                                               float* __restrict__ norms) {
    int row = blockIdx.x;                      // 0..8191
    int tid = threadIdx.x;
    const float* p = pf + (size_t)row * DD + tid * 16;
    size_t o = (size_t)row * DD + tid * 16;
    float s = 0.f;
#pragma unroll
    for (int half = 0; half < 2; ++half) {
        float4 v0 = *(const float4*)(p + half * 8);
        float4 v1 = *(const float4*)(p + half * 8 + 4);
        float x[8] = {v0.x, v0.y, v0.z, v0.w, v1.x, v1.y, v1.z, v1.w};
        unsigned hw[4], lw[4];
#pragma unroll
        for (int e = 0; e < 4; ++e) {
            float a = x[2 * e], b = x[2 * e + 1];
            s = fmaf(a, a, fmaf(b, b, s));
            unsigned short ha = f2bf(a), hb = f2bf(b);
            unsigned short la = f2bf(a - bf2f(ha));
            unsigned short lb = f2bf(b - bf2f(hb));
            hw[e] = (unsigned)ha | ((unsigned)hb << 16);
            lw[e] = (unsigned)la | ((unsigned)lb << 16);
        }
        *(uint4*)(ph + o + half * 8) = make_uint4(hw[0], hw[1], hw[2], hw[3]);
        *(uint4*)(pl + o + half * 8) = make_uint4(lw[0], lw[1], lw[2], lw[3]);
    }
    for (int off = 32; off; off >>= 1) s += __shfl_down(s, off);
    __shared__ float wsum[4];
    if ((tid & 63) == 0) wsum[tid >> 6] = s;
    __syncthreads();
    if (tid == 0) norms[row] = wsum[0] + wsum[1] + wsum[2] + wsum[3];
}

// ---------------------------------------------------------------------------
// MFMA pair matching. Tile 128x128, BK=32, 4 waves (2x2), bf16 split-GEMM
// (4 passes: AhBh+AhBl+AlBh+AlBl), fused metric + column-max epilogue.
__global__ __launch_bounds__(256) void k_match_mfma(const unsigned short* __restrict__ ph,
                                                    const unsigned short* __restrict__ pl,
                                                    const float* __restrict__ rois,
                                                    const float* __restrict__ norms,
                                                    unsigned long long* __restrict__ keys) {
    const int t  = blockIdx.z;
    const int ib = blockIdx.y * 128;
    const int jb = blockIdx.x * 128;
    const unsigned short* Ahg = ph + (size_t)t * RR * DD;
    const unsigned short* Alg = pl + (size_t)t * RR * DD;
    const unsigned short* Bhg = ph + (size_t)(t + 1) * RR * DD;
    const unsigned short* Blg = pl + (size_t)(t + 1) * RR * DD;

    __shared__ __align__(16) unsigned short Ah[128 * 32], Al[128 * 32];
    __shared__ __align__(16) unsigned short Bh[128 * 32], Bl[128 * 32];
    __shared__ float4 ra4s[128], rb4s[128];

    char* ldsAh = (char*)Ah; char* ldsAl = (char*)Al;
    char* ldsBh = (char*)Bh; char* ldsBl = (char*)Bl;

    const int tid = threadIdx.x;
    if (tid < 128) ra4s[tid] = *(const float4*)(rois + ((size_t)t * RR + ib + tid) * 4);
    else           rb4s[tid - 128] = *(const float4*)(rois + ((size_t)(t + 1) * RR + jb + (tid - 128)) * 4);

    // staging map: rows sr, sr+64 ; seg ss (8 bf16 = 16B)
    const int sr = tid >> 2;           // 0..63
    const int ss = tid & 3;            // 0..3
    const size_t a0 = (size_t)(ib + sr) * DD + ss * 8;
    const size_t a1 = (size_t)(ib + 64 + sr) * DD + ss * 8;
    const size_t b0 = (size_t)(jb + sr) * DD + ss * 8;
    const size_t b1 = (size_t)(jb + 64 + sr) * DD + ss * 8;
    // swizzled LDS byte offsets: row*64 + ((ss ^ ((row>>1)&3))*16); rows +64 keep same xor
    const int lb0 = sr * 64 + ((ss ^ ((sr >> 1) & 3)) * 16);
    const int lb1 = lb0 + 64 * 64;

    // wave / fragment ids
    const int wid = tid >> 6, lane = tid & 63;
    const int wr = wid >> 1, wc = wid & 1;
    const int fr = lane & 15, fg = lane >> 4;

    // fragment LDS byte offsets (loop-invariant, swizzled)
    int fba[4], fbb[4];
#pragma unroll
    for (int m = 0; m < 4; ++m) {
        int r = wr * 64 + m * 16 + fr;
        fba[m] = r * 64 + ((fg ^ ((r >> 1) & 3)) * 16);
    }
#pragma unroll
    for (int n = 0; n < 4; ++n) {
        int r = wc * 64 + n * 16 + fr;
        fbb[n] = r * 64 + ((fg ^ ((r >> 1) & 3)) * 16);
    }

    f32x4 acc[4][4];
#pragma unroll
    for (int m = 0; m < 4; ++m)
#pragma unroll
        for (int n = 0; n < 4; ++n) acc[m][n] = (f32x4){0.f, 0.f, 0.f, 0.f};

    uint4 vah0, vah1, val0, val1, vbh0, vbh1, vbl0, vbl1;
    auto LOADG = [&](int k0) {
        vah0 = *(const uint4*)(Ahg + a0 + k0); vah1 = *(const uint4*)(Ahg + a1 + k0);
        val0 = *(const uint4*)(Alg + a0 + k0); val1 = *(const uint4*)(Alg + a1 + k0);
        vbh0 = *(const uint4*)(Bhg + b0 + k0); vbh1 = *(const uint4*)(Bhg + b1 + k0);
        vbl0 = *(const uint4*)(Blg + b0 + k0); vbl1 = *(const uint4*)(Blg + b1 + k0);
    };

    LOADG(0);
    for (int kk = 0; kk < DD / 32; ++kk) {
        __syncthreads();                        // prev tile's reads done
        *(uint4*)(ldsAh + lb0) = vah0; *(uint4*)(ldsAh + lb1) = vah1;
        *(uint4*)(ldsAl + lb0) = val0; *(uint4*)(ldsAl + lb1) = val1;
        *(uint4*)(ldsBh + lb0) = vbh0; *(uint4*)(ldsBh + lb1) = vbh1;
        *(uint4*)(ldsBl + lb0) = vbl0; *(uint4*)(ldsBl + lb1) = vbl1;
        __syncthreads();                        // writes visible
        if (kk + 1 < DD / 32) LOADG((kk + 1) * 32);   // in flight across compute

        bf16x8 ah[4], al[4], bh[4], bl[4];
#pragma unroll
        for (int m = 0; m < 4; ++m) {
            ah[m] = *(const bf16x8*)(ldsAh + fba[m]);
            al[m] = *(const bf16x8*)(ldsAl + fba[m]);
        }
#pragma unroll
        for (int n = 0; n < 4; ++n) {
            bh[n] = *(const bf16x8*)(ldsBh + fbb[n]);
            bl[n] = *(const bf16x8*)(ldsBl + fbb[n]);
        }
#pragma unroll
        for (int m = 0; m < 4; ++m)
#pragma unroll
            for (int n = 0; n < 4; ++n) {
                f32x4 c = acc[m][n];
                c = __builtin_amdgcn_mfma_f32_16x16x32_bf16(ah[m], bh[n], c, 0, 0, 0);
                c = __builtin_amdgcn_mfma_f32_16x16x32_bf16(ah[m], bl[n], c, 0, 0, 0);
                c = __builtin_amdgcn_mfma_f32_16x16x32_bf16(al[m], bh[n], c, 0, 0, 0);
                c = __builtin_amdgcn_mfma_f32_16x16x32_bf16(al[m], bl[n], c, 0, 0, 0);
                acc[m][n] = c;
            }
    }

    // ---- epilogue: metric + column-max ----
    const float* nA = norms + t * RR + ib;
    const float* nB = norms + (t + 1) * RR + jb;

    int jl[4]; float4 Bb[4]; float nbv[4], areab[4];
    unsigned long long best[4];
#pragma unroll
    for (int n = 0; n < 4; ++n) {
        jl[n] = wc * 64 + n * 16 + fr;
        Bb[n] = rb4s[jl[n]];
        nbv[n] = nB[jl[n]];
        areab[n] = (Bb[n].z - Bb[n].x + 1.f) * (Bb[n].w - Bb[n].y + 1.f);
        best[n] = 0ull;
    }
#pragma unroll
    for (int m = 0; m < 4; ++m)
#pragma unroll
        for (int rg = 0; rg < 4; ++rg) {
            int il = wr * 64 + m * 16 + fg * 4 + rg;
            float nav = nA[il];
            float4 A = ra4s[il];
            float areaa = (A.z - A.x + 1.f) * (A.w - A.y + 1.f);
            unsigned long long ikey = (unsigned long long)(unsigned)(RR - 1 - (ib + il));
#pragma unroll
            for (int n = 0; n < 4; ++n) {
                float c = acc[m][n][rg];
                float d2 = fmaxf(nav + nbv[n] - 2.f * c, 0.f);
                float drev = 1.f / (1.f + sqrtf(d2));
                float iw = fmaxf(fminf(A.z, Bb[n].z) - fmaxf(A.x, Bb[n].x) + 1.f, 0.f);
                float ih = fmaxf(fminf(A.w, Bb[n].w) - fmaxf(A.y, Bb[n].y) + 1.f, 0.f);
                float inter = iw * ih;
                float iou = inter / (areaa + areab[n] - inter);
                float mt = iou + drev;
                unsigned long long key = ((unsigned long long)__float_as_uint(mt) << 32) | ikey;
                best[n] = u64max(best[n], key);
            }
        }
#pragma unroll
    for (int n = 0; n < 4; ++n) {
        unsigned long long b = best[n];
        b = u64max(b, __shfl_xor(b, 16, 64));
        b = u64max(b, __shfl_xor(b, 32, 64));
        if (fg == 0) atomicMax(&keys[(size_t)t * RR + jb + jl[n]], b);
    }
}

// ---------------------------------------------------------------------------
// Fallback f32 matcher (used only if ws too small for split buffers).
__global__ __launch_bounds__(256) void k_norms(const float* __restrict__ pf,
                                               float* __restrict__ norms) {
    int row = blockIdx.x;
    const float* p = pf + (size_t)row * DD;
    int tid = threadIdx.x;
    float s = 0.f;
    for (int d = tid * 4; d < DD; d += 1024) {
        float4 v = *(const float4*)(p + d);
        s = fmaf(v.x, v.x, s); s = fmaf(v.y, v.y, s);
        s = fmaf(v.z, v.z, s); s = fmaf(v.w, v.w, s);
    }
    for (int off = 32; off; off >>= 1) s += __shfl_down(s, off);
    __shared__ float wsum[4];
    int wid = tid >> 6, lane = tid & 63;
    if (lane == 0) wsum[wid] = s;
    __syncthreads();
    if (tid == 0) norms[row] = wsum[0] + wsum[1] + wsum[2] + wsum[3];
}

__global__ __launch_bounds__(256) void k_match(const float* __restrict__ pf,
                                               const float* __restrict__ rois,
                                               const float* __restrict__ norms,
                                               unsigned long long* __restrict__ keys) {
    const int t  = blockIdx.z;
    const int ib = blockIdx.y * 64;
    const int jb = blockIdx.x * 64;
    const float* fa = pf + (size_t)t * RR * DD;
    const float* fb = pf + (size_t)(t + 1) * RR * DD;

    __shared__ float As[32][68];
    __shared__ float Bs[32][68];
    __shared__ float4 ra4[64];
    __shared__ float4 rb4[64];
    __shared__ unsigned long long red[16][64];

    const int tid = threadIdx.x;
    const int tx = tid & 15;
    const int ty = tid >> 4;

    if (tid < 64) {
        ra4[tid] = *(const float4*)(rois + ((size_t)t * RR + ib + tid) * 4);
        rb4[tid] = *(const float4*)(rois + ((size_t)(t + 1) * RR + jb + tid) * 4);
    }

    float acc[4][4];
#pragma unroll
    for (int u = 0; u < 4; ++u)
#pragma unroll
        for (int v = 0; v < 4; ++v) acc[u][v] = 0.f;

    const int lr = tid >> 3;
    const int lk = (tid & 7) * 4;

    for (int k0 = 0; k0 < DD; k0 += 32) {
        float4 a0 = *(const float4*)(fa + (size_t)(ib + lr) * DD + k0 + lk);
        float4 a1 = *(const float4*)(fa + (size_t)(ib + lr + 32) * DD + k0 + lk);
        float4 b0 = *(const float4*)(fb + (size_t)(jb + lr) * DD + k0 + lk);
        float4 b1 = *(const float4*)(fb + (size_t)(jb + lr + 32) * DD + k0 + lk);
        __syncthreads();
        As[lk + 0][lr] = a0.x; As[lk + 1][lr] = a0.y; As[lk + 2][lr] = a0.z; As[lk + 3][lr] = a0.w;
        As[lk + 0][lr + 32] = a1.x; As[lk + 1][lr + 32] = a1.y; As[lk + 2][lr + 32] = a1.z; As[lk + 3][lr + 32] = a1.w;
        Bs[lk + 0][lr] = b0.x; Bs[lk + 1][lr] = b0.y; Bs[lk + 2][lr] = b0.z; Bs[lk + 3][lr] = b0.w;
        Bs[lk + 0][lr + 32] = b1.x; Bs[lk + 1][lr + 32] = b1.y; Bs[lk + 2][lr + 32] = b1.z; Bs[lk + 3][lr + 32] = b1.w;
        __syncthreads();
#pragma unroll
        for (int kkk = 0; kkk < 32; ++kkk) {
            float4 av = *(const float4*)&As[kkk][ty * 4];
            float4 bv = *(const float4*)&Bs[kkk][tx * 4];
            float a_[4] = {av.x, av.y, av.z, av.w};
            float b_[4] = {bv.x, bv.y, bv.z, bv.w};
#pragma unroll
            for (int u = 0; u < 4; ++u)
#pragma unroll
                for (int v = 0; v < 4; ++v)
                    acc[u][v] = fmaf(a_[u], b_[v], acc[u][v]);
        }
    }
    __syncthreads();

    float na[4], nb_[4];
#pragma unroll
    for (int u = 0; u < 4; ++u) na[u]  = norms[t * RR + ib + ty * 4 + u];
#pragma unroll
    for (int v = 0; v < 4; ++v) nb_[v] = norms[(t + 1) * RR + jb + tx * 4 + v];

#pragma unroll
    for (int v = 0; v < 4; ++v) {
        unsigned long long bestkey = 0ull;
        float4 B = rb4[tx * 4 + v];
        float area_b = (B.z - B.x + 1.f) * (B.w - B.y + 1.f);
#pragma unroll
        for (int u = 0; u < 4; ++u) {
            float d2 = fmaxf(na[u] + nb_[v] - 2.f * acc[u][v], 0.f);
            float drev = 1.f / (1.f + sqrtf(d2));
            float4 A = ra4[ty * 4 + u];
            float area_a = (A.z - A.x + 1.f) * (A.w - A.y + 1.f);
            float iw = fmaxf(fminf(A.z, B.z) - fmaxf(A.x, B.x) + 1.f, 0.f);
            float ih = fmaxf(fminf(A.w, B.w) - fmaxf(A.y, B.y) + 1.f, 0.f);
            float inter = iw * ih;
            float iou = inter / (area_a + area_b - inter);
            float m = iou + drev;
            int gi = ib + ty * 4 + u;
            unsigned long long key =
                ((unsigned long long)__float_as_uint(m) << 32) |
                (unsigned long long)(unsigned)(RR - 1 - gi);
            if (key > bestkey) bestkey = key;
        }
        red[ty][tx * 4 + v] = bestkey;
    }
    __syncthreads();
    if (tid < 64) {
        unsigned long long best = red[0][tid];
#pragma unroll
        for (int r = 1; r < 16; ++r) {
            unsigned long long k = red[r][tid];
            if (k > best) best = k;
        }
        atomicMax(&keys[(size_t)t * RR + jb + tid], best);
    }
}

// ---------------------------------------------------------------------------
// Finalize: decode keys -> (val, idx); complete = all vals >= 1.0; scan.
__global__ __launch_bounds__(512) void k_finalize(const unsigned long long* __restrict__ keys,
                                                  const int* __restrict__ rlabel,
                                                  int* __restrict__ idx_all,
                                                  int* __restrict__ src,
                                                  int* __restrict__ lblS,
                                                  int* __restrict__ ncomp) {
    __shared__ int sc[RR];
    int j = threadIdx.x;
    bool comp = true;
#pragma unroll
    for (int t = 0; t < NPAIR; ++t) {
        unsigned long long k = keys[t * RR + j];
        float v = __uint_as_float((unsigned)(k >> 32));
        idx_all[t * RR + j] = (RR - 1) - (int)(k & 0xffffffffu);
        comp = comp && (v >= 1.0f);   // THR = 1.0
    }
    sc[j] = comp ? 1 : 0;
    __syncthreads();
    for (int off = 1; off < RR; off <<= 1) {
        int v = sc[j];
        int a = (j >= off) ? sc[j - off] : 0;
        __syncthreads();
        sc[j] = v + a;
        __syncthreads();
    }
    if (comp) {
        int pos = sc[j] - 1;
        src[pos] = j;
        int s = 0;
#pragma unroll
        for (int t = 0; t < T_WIN; ++t) s += rlabel[t * RR + j];
        int ref = rlabel[j];
        lblS[pos] = ((s / T_WIN) == ref) ? ref : 0;
    }
    if (j == RR - 1) *ncomp = sc[RR - 1];
}

// ---------------------------------------------------------------------------
// Heads: one block per output row.
__global__ __launch_bounds__(256) void k_heads(const float* __restrict__ pf,
                                               const float* __restrict__ Wt,
                                               const float* __restrict__ bc,
                                               const float* __restrict__ bbias,
                                               const int* __restrict__ src,
                                               const int* __restrict__ lblS,
                                               const int* __restrict__ ncompp,
                                               const int* __restrict__ idx_all,
                                               float* __restrict__ out) {
    __shared__ float feat[DD];
    __shared__ float scores[NHEAD];
    __shared__ int ridx[NPAIR];
    __shared__ float mx, sm;

    int r = blockIdx.x;
    int tid = threadIdx.x;
    int ncomp = *ncompp;
    bool comp = (r < ncomp);

    if (comp) {
        int j = src[r];
        if (tid < NPAIR) ridx[tid] = idx_all[tid * RR + j];
        __syncthreads();
        for (int d = tid * 4; d < DD; d += 1024) {
            float4 s = *(const float4*)(pf + (size_t)j * DD + d);
#pragma unroll
            for (int t = 0; t < NPAIR; ++t) {
                float4 g = *(const float4*)(pf + ((size_t)(t + 1) * RR + ridx[t]) * DD + d);
                s.x += g.x; s.y += g.y; s.z += g.z; s.w += g.w;
            }
            *(float4*)&feat[d] = s;
        }
        __syncthreads();
        int wid = tid >> 6, lane = tid & 63;
        for (int o = wid; o < NHEAD; o += 4) {
            const float* w = Wt + (size_t)o * DD;
            float s = 0.f;
            for (int d = lane * 4; d < DD; d += 256) {
                float4 wv = *(const float4*)(w + d);
                float4 fv = *(const float4*)&feat[d];
                s = fmaf(wv.x, fv.x, s); s = fmaf(wv.y, fv.y, s);
                s = fmaf(wv.z, fv.z, s); s = fmaf(wv.w, fv.w, s);
            }
            for (int off = 32; off; off >>= 1) s += __shfl_down(s, off);
            if (lane == 0) scores[o] = s + (o < NCLS ? bc[o] : bbias[o - NCLS]);
        }
        __syncthreads();
    } else {
        if (tid < NHEAD) scores[tid] = (tid < NCLS ? bc[tid] : bbias[tid - NCLS]);
        __syncthreads();
    }

    if (tid == 0) {
        float m = scores[0];
        for (int c = 1; c < NCLS; ++c) m = fmaxf(m, scores[c]);
        float s = 0.f;
        for (int c = 0; c < NCLS; ++c) s += expf(scores[c] - m);
        mx = m; sm = s;
    }
    __syncthreads();

    float* cls = out;
    float* bb  = out + (size_t)NOUT * NCLS;
    float* lb  = out + (size_t)NOUT * (NCLS + NBB);
    if (tid < NCLS) cls[(size_t)r * NCLS + tid] = expf(scores[tid] - mx) / sm;
    if (tid < NBB)  bb[(size_t)r * NBB + tid]   = scores[NCLS + tid];
    if (tid == 0)   lb[r] = comp ? (float)lblS[r] : 0.f;
}

// ---------------------------------------------------------------------------
extern "C" void kernel_launch(void* const* d_in, const int* in_sizes, int n_in,
                              void* d_out, int out_size, void* d_ws, size_t ws_size,
                              hipStream_t stream) {
    (void)in_sizes; (void)n_in; (void)out_size;
    const float* pf   = (const float*)d_in[0];
    const float* rois = (const float*)d_in[1];
    const int*   rlab = (const int*)d_in[2];
    const float* Wc   = (const float*)d_in[3];
    const float* bc   = (const float*)d_in[4];
    const float* Wb   = (const float*)d_in[5];
    const float* bbv  = (const float*)d_in[6];

    char* ws = (char*)d_ws;
    float*              norms   = (float*)(ws + OFF_NORMS);
    unsigned long long* keys    = (unsigned long long*)(ws + OFF_KEYS);
    int*                idx_all = (int*)(ws + OFF_IDX);
    int*                src     = (int*)(ws + OFF_SRC);
    int*                lblS    = (int*)(ws + OFF_LBL);
    int*                ncomp   = (int*)(ws + OFF_NCMP);
    float*              Wt      = (float*)(ws + OFF_WT);
    unsigned short*     ph      = (unsigned short*)(ws + OFF_PH);
    unsigned short*     pl      = (unsigned short*)(ws + OFF_PL);
    float*              out     = (float*)d_out;

    k_prep<<<dim3(2480), dim3(256), 0, stream>>>(keys, Wc, Wb, Wt);
    if (ws_size >= (size_t)WS_NEED) {
        k_split<<<dim3(NOUT), dim3(256), 0, stream>>>(pf, ph, pl, norms);
        k_match_mfma<<<dim3(4, 4, NPAIR), dim3(256), 0, stream>>>(ph, pl, rois, norms, keys);
    } else {
        k_norms<<<dim3(NOUT), dim3(256), 0, stream>>>(pf, norms);
        k_match<<<dim3(8, 8, NPAIR), dim3(256), 0, stream>>>(pf, rois, norms, keys);
    }
    k_finalize<<<dim3(1), dim3(512), 0, stream>>>(keys, rlab, idx_all, src, lblS, ncomp);
    k_heads<<<dim3(NOUT), dim3(256), 0, stream>>>(pf, Wt, bc, bbv, src, lblS, ncomp, idx_all, out);
}

// Round 8
// 506.769 us; speedup vs baseline: 1.7644x; 1.4740x over previous
//
#include <hip/hip_runtime.h>
#include <hip/hip_bf16.h>

// Problem constants (VID tube linking)
#define T_WIN 16
#define RR    512
#define DD    4096
#define NCLS  31
#define NBB   124          // 4*NCLS
#define NPAIR 15           // T_WIN-1
#define NOUT  (T_WIN*RR)   // 8192
#define NHEAD (NCLS+NBB)   // 155
#define KC_N  16           // K-chunks for k_dots
#define KCS   (DD/KC_N)    // 256
#define RT    8            // rows per k_dots block

// Workspace layout (bytes).
#define OFF_NORMS 0u          // f32[8192]
#define OFF_KEYS  32768u      // u64[15*512]
#define OFF_IDX   98304u      // i32[15*512]
#define OFF_SRC   131072u     // i32[512]
#define OFF_LBL   135168u     // i32[512]
#define OFF_NCMP  139264u     // i32[1]
#define OFF_DCLS  143360u     // f32[31]  (softmax of b_cls for dead rows)
#define OFF_WT    262144u     // f32[155*4096]
#define OFF_PH    4194304u    // bf16[8192*4096]  (hi)
#define OFF_PL    71303168u   // bf16[8192*4096]  (lo)
#define OFF_FEAT  138412032u  // f32[512*4096]    (gathered tube feats)
#define OFF_PART  146800640u  // f32[16*512*160]  (K-split partial scores)
#define WS_NEED   152043520u

typedef __bf16 bf16x8 __attribute__((ext_vector_type(8)));
typedef float  f32x4  __attribute__((ext_vector_type(4)));

__device__ __forceinline__ unsigned short f2bf(float f) {
    unsigned u = __float_as_uint(f);
    unsigned r = (u + 0x7fffu + ((u >> 16) & 1u)) >> 16;   // RNE
    return (unsigned short)r;
}
__device__ __forceinline__ float bf2f(unsigned short h) {
    return __uint_as_float(((unsigned)h) << 16);
}
__device__ __forceinline__ unsigned long long u64max(unsigned long long a, unsigned long long b) {
    return a > b ? a : b;
}

// ---------------------------------------------------------------------------
// Prep: zero packed max-keys; build Wt = [W_cls | W_bbox]^T; dead-row softmax.
__global__ __launch_bounds__(256) void k_prep(unsigned long long* __restrict__ keys,
                                              const float* __restrict__ Wc,
                                              const float* __restrict__ Wb,
                                              const float* __restrict__ bc,
                                              float* __restrict__ Wt,
                                              float* __restrict__ dcls) {
    int i = blockIdx.x * 256 + threadIdx.x;
    if (i < NPAIR * RR) keys[i] = 0ull;
    if (i < NHEAD * DD) {
        int d = i & (DD - 1);
        int o = i >> 12;                       // DD = 4096 = 2^12
        Wt[i] = (o < NCLS) ? Wc[d * NCLS + o] : Wb[d * NBB + (o - NCLS)];
    }
    // wave 0 of block 0: softmax(b_cls) for dead output rows
    if (blockIdx.x == 0 && threadIdx.x < 64) {
        int t = threadIdx.x;
        float v = (t < NCLS) ? bc[t] : -3.4e38f;
        float mx = v;
        for (int m = 32; m; m >>= 1) mx = fmaxf(mx, __shfl_xor(mx, m));
        float e = (t < NCLS) ? expf(v - mx) : 0.f;
        float sm = e;
        for (int m = 32; m; m >>= 1) sm += __shfl_xor(sm, m);
        if (t < NCLS) dcls[t] = e / sm;
    }
}

// ---------------------------------------------------------------------------
// Split f32 -> (hi,lo) bf16 + fused row squared-norms. One block per row.
__global__ __launch_bounds__(256) void k_split(const float* __restrict__ pf,
                                               unsigned short* __restrict__ ph,
                                               unsigned short* __restrict__ pl,
                                               float* __restrict__ norms) {
    int row = blockIdx.x;                      // 0..8191
    int tid = threadIdx.x;
    const float* p = pf + (size_t)row * DD + tid * 16;
    size_t o = (size_t)row * DD + tid * 16;
    float s = 0.f;
#pragma unroll
    for (int half = 0; half < 2; ++half) {
        float4 v0 = *(const float4*)(p + half * 8);
        float4 v1 = *(const float4*)(p + half * 8 + 4);
        float x[8] = {v0.x, v0.y, v0.z, v0.w, v1.x, v1.y, v1.z, v1.w};
        unsigned hw[4], lw[4];
#pragma unroll
        for (int e = 0; e < 4; ++e) {
            float a = x[2 * e], b = x[2 * e + 1];
            s = fmaf(a, a, fmaf(b, b, s));
            unsigned short ha = f2bf(a), hb = f2bf(b);
            unsigned short la = f2bf(a - bf2f(ha));
            unsigned short lb = f2bf(b - bf2f(hb));
            hw[e] = (unsigned)ha | ((unsigned)hb << 16);
            lw[e] = (unsigned)la | ((unsigned)lb << 16);
        }
        *(uint4*)(ph + o + half * 8) = make_uint4(hw[0], hw[1], hw[2], hw[3]);
        *(uint4*)(pl + o + half * 8) = make_uint4(lw[0], lw[1], lw[2], lw[3]);
    }
    for (int off = 32; off; off >>= 1) s += __shfl_down(s, off);
    __shared__ float wsum[4];
    if ((tid & 63) == 0) wsum[tid >> 6] = s;
    __syncthreads();
    if (tid == 0) norms[row] = wsum[0] + wsum[1] + wsum[2] + wsum[3];
}

// ---------------------------------------------------------------------------
// MFMA pair matching v2. 64x64 tiles -> 960 blocks (~4/CU), BK=64,
// 4 waves (2x2, each 32x32 out), 4-pass split-bf16, fused epilogue.
// LDS swizzle: row stride 128B; seg slot = ss ^ (row&7) -> conflict-free
// for both staging writes (lane=(r,ss)) and frag reads (lane=(fr,fg)).
__global__ __launch_bounds__(256, 4) void k_match_mfma(const unsigned short* __restrict__ ph,
                                                       const unsigned short* __restrict__ pl,
                                                       const float* __restrict__ rois,
                                                       const float* __restrict__ norms,
                                                       unsigned long long* __restrict__ keys) {
    const int t  = blockIdx.z;
    const int ib = blockIdx.y * 64;
    const int jb = blockIdx.x * 64;
    const unsigned short* Ahg = ph + (size_t)t * RR * DD;
    const unsigned short* Alg = pl + (size_t)t * RR * DD;
    const unsigned short* Bhg = ph + (size_t)(t + 1) * RR * DD;
    const unsigned short* Blg = pl + (size_t)(t + 1) * RR * DD;

    __shared__ __align__(16) unsigned short Ah[64 * 64], Al[64 * 64];
    __shared__ __align__(16) unsigned short Bh[64 * 64], Bl[64 * 64];
    __shared__ float4 ra4s[64], rb4s[64];

    char* ldsAh = (char*)Ah; char* ldsAl = (char*)Al;
    char* ldsBh = (char*)Bh; char* ldsBl = (char*)Bl;

    const int tid = threadIdx.x;
    if (tid < 64)       ra4s[tid]      = *(const float4*)(rois + ((size_t)t * RR + ib + tid) * 4);
    else if (tid < 128) rb4s[tid - 64] = *(const float4*)(rois + ((size_t)(t + 1) * RR + jb + (tid - 64)) * 4);

    // staging: thread -> rows sr, sr+32 ; seg ss (8 bf16 = 16B), 8 segs/row
    const int sr = tid >> 3;           // 0..31
    const int ss = tid & 7;            // 0..7
    const size_t a0 = (size_t)(ib + sr) * DD + ss * 8;
    const size_t a1 = a0 + (size_t)32 * DD;
    const size_t b0 = (size_t)(jb + sr) * DD + ss * 8;
    const size_t b1 = b0 + (size_t)32 * DD;
    const int l0 = sr * 128 + ((ss ^ (sr & 7)) * 16);
    const int l1 = l0 + 32 * 128;      // (sr+32)&7 == sr&7 -> same slot xor

    // wave / fragment ids
    const int wid = tid >> 6, lane = tid & 63;
    const int wr = wid >> 1, wc = wid & 1;     // 2x2 waves, 32x32 out each
    const int fr = lane & 15, fg = lane >> 4;

    // fragment LDS byte offsets: frag (m, ksub s): row = w*32+m*16+fr,
    // seg = s*4+fg, slot = seg ^ (row&7)
    int fba[2][2], fbb[2][2];
#pragma unroll
    for (int m = 0; m < 2; ++m) {
        int r = wr * 32 + m * 16 + fr;
#pragma unroll
        for (int s = 0; s < 2; ++s)
            fba[m][s] = r * 128 + (((s * 4 + fg) ^ (r & 7)) * 16);
    }
#pragma unroll
    for (int n = 0; n < 2; ++n) {
        int r = wc * 32 + n * 16 + fr;
#pragma unroll
        for (int s = 0; s < 2; ++s)
            fbb[n][s] = r * 128 + (((s * 4 + fg) ^ (r & 7)) * 16);
    }

    f32x4 acc[2][2];
#pragma unroll
    for (int m = 0; m < 2; ++m)
#pragma unroll
        for (int n = 0; n < 2; ++n) acc[m][n] = (f32x4){0.f, 0.f, 0.f, 0.f};

    uint4 vah0, vah1, val0, val1, vbh0, vbh1, vbl0, vbl1;
    auto LOADG = [&](int k0) {
        vah0 = *(const uint4*)(Ahg + a0 + k0); vah1 = *(const uint4*)(Ahg + a1 + k0);
        val0 = *(const uint4*)(Alg + a0 + k0); val1 = *(const uint4*)(Alg + a1 + k0);
        vbh0 = *(const uint4*)(Bhg + b0 + k0); vbh1 = *(const uint4*)(Bhg + b1 + k0);
        vbl0 = *(const uint4*)(Blg + b0 + k0); vbl1 = *(const uint4*)(Blg + b1 + k0);
    };

    LOADG(0);
    for (int kk = 0; kk < DD / 64; ++kk) {
        __syncthreads();                        // prev tile's reads done
        *(uint4*)(ldsAh + l0) = vah0; *(uint4*)(ldsAh + l1) = vah1;
        *(uint4*)(ldsAl + l0) = val0; *(uint4*)(ldsAl + l1) = val1;
        *(uint4*)(ldsBh + l0) = vbh0; *(uint4*)(ldsBh + l1) = vbh1;
        *(uint4*)(ldsBl + l0) = vbl0; *(uint4*)(ldsBl + l1) = vbl1;
        __syncthreads();                        // writes visible
        if (kk + 1 < DD / 64) LOADG((kk + 1) * 64);   // in flight across compute

#pragma unroll
        for (int s = 0; s < 2; ++s) {
            bf16x8 ah[2], al[2], bh[2], bl[2];
#pragma unroll
            for (int m = 0; m < 2; ++m) {
                ah[m] = *(const bf16x8*)(ldsAh + fba[m][s]);
                al[m] = *(const bf16x8*)(ldsAl + fba[m][s]);
            }
#pragma unroll
            for (int n = 0; n < 2; ++n) {
                bh[n] = *(const bf16x8*)(ldsBh + fbb[n][s]);
                bl[n] = *(const bf16x8*)(ldsBl + fbb[n][s]);
            }
#pragma unroll
            for (int m = 0; m < 2; ++m)
#pragma unroll
                for (int n = 0; n < 2; ++n) {
                    f32x4 c = acc[m][n];
                    c = __builtin_amdgcn_mfma_f32_16x16x32_bf16(ah[m], bh[n], c, 0, 0, 0);
                    c = __builtin_amdgcn_mfma_f32_16x16x32_bf16(ah[m], bl[n], c, 0, 0, 0);
                    c = __builtin_amdgcn_mfma_f32_16x16x32_bf16(al[m], bh[n], c, 0, 0, 0);
                    c = __builtin_amdgcn_mfma_f32_16x16x32_bf16(al[m], bl[n], c, 0, 0, 0);
                    acc[m][n] = c;
                }
        }
    }

    // ---- epilogue: metric + column-max ----
    const float* nA = norms + t * RR + ib;
    const float* nB = norms + (t + 1) * RR + jb;

    int jl[2]; float4 Bb[2]; float nbv[2], areab[2];
    unsigned long long best[2];
#pragma unroll
    for (int n = 0; n < 2; ++n) {
        jl[n] = wc * 32 + n * 16 + fr;
        Bb[n] = rb4s[jl[n]];
        nbv[n] = nB[jl[n]];
        areab[n] = (Bb[n].z - Bb[n].x + 1.f) * (Bb[n].w - Bb[n].y + 1.f);
        best[n] = 0ull;
    }
#pragma unroll
    for (int m = 0; m < 2; ++m)
#pragma unroll
        for (int rg = 0; rg < 4; ++rg) {
            int il = wr * 32 + m * 16 + fg * 4 + rg;
            float nav = nA[il];
            float4 A = ra4s[il];
            float areaa = (A.z - A.x + 1.f) * (A.w - A.y + 1.f);
            unsigned long long ikey = (unsigned long long)(unsigned)(RR - 1 - (ib + il));
#pragma unroll
            for (int n = 0; n < 2; ++n) {
                float c = acc[m][n][rg];
                float d2 = fmaxf(nav + nbv[n] - 2.f * c, 0.f);
                float drev = 1.f / (1.f + sqrtf(d2));
                float iw = fmaxf(fminf(A.z, Bb[n].z) - fmaxf(A.x, Bb[n].x) + 1.f, 0.f);
                float ih = fmaxf(fminf(A.w, Bb[n].w) - fmaxf(A.y, Bb[n].y) + 1.f, 0.f);
                float inter = iw * ih;
                float iou = inter / (areaa + areab[n] - inter);
                float mt = iou + drev;
                unsigned long long key = ((unsigned long long)__float_as_uint(mt) << 32) | ikey;
                best[n] = u64max(best[n], key);
            }
        }
#pragma unroll
    for (int n = 0; n < 2; ++n) {
        unsigned long long b = best[n];
        b = u64max(b, __shfl_xor(b, 16, 64));
        b = u64max(b, __shfl_xor(b, 32, 64));
        if (fg == 0) atomicMax(&keys[(size_t)t * RR + jb + jl[n]], b);
    }
}

// ---------------------------------------------------------------------------
// Finalize: decode keys -> (val, idx); complete = all vals >= 1.0; scan.
__global__ __launch_bounds__(512) void k_finalize(const unsigned long long* __restrict__ keys,
                                                  const int* __restrict__ rlabel,
                                                  int* __restrict__ idx_all,
                                                  int* __restrict__ src,
                                                  int* __restrict__ lblS,
                                                  int* __restrict__ ncomp) {
    __shared__ int sc[RR];
    int j = threadIdx.x;
    bool comp = true;
#pragma unroll
    for (int t = 0; t < NPAIR; ++t) {
        unsigned long long k = keys[t * RR + j];
        float v = __uint_as_float((unsigned)(k >> 32));
        idx_all[t * RR + j] = (RR - 1) - (int)(k & 0xffffffffu);
        comp = comp && (v >= 1.0f);   // THR = 1.0
    }
    sc[j] = comp ? 1 : 0;
    __syncthreads();
    for (int off = 1; off < RR; off <<= 1) {
        int v = sc[j];
        int a = (j >= off) ? sc[j - off] : 0;
        __syncthreads();
        sc[j] = v + a;
        __syncthreads();
    }
    if (comp) {
        int pos = sc[j] - 1;
        src[pos] = j;
        int s = 0;
#pragma unroll
        for (int t = 0; t < T_WIN; ++t) s += rlabel[t * RR + j];
        int ref = rlabel[j];
        lblS[pos] = ((s / T_WIN) == ref) ? ref : 0;
    }
    if (j == RR - 1) *ncomp = sc[RR - 1];
}

// ---------------------------------------------------------------------------
// Heads phase A: gather tube features for live rows -> featW f32 [512][4096].
__global__ __launch_bounds__(256) void k_gather(const float* __restrict__ pf,
                                                const int* __restrict__ src,
                                                const int* __restrict__ ncompp,
                                                const int* __restrict__ idx_all,
                                                float* __restrict__ featW) {
    int r = blockIdx.x;
    if (r >= *ncompp) return;
    int j = src[r];
    __shared__ int ridx[NPAIR];
    int tid = threadIdx.x;
    if (tid < NPAIR) ridx[tid] = idx_all[tid * RR + j];
    __syncthreads();
    for (int d = tid * 4; d < DD; d += 1024) {
        float4 s = *(const float4*)(pf + (size_t)j * DD + d);   // frame 0
#pragma unroll
        for (int t = 0; t < NPAIR; ++t) {
            float4 g = *(const float4*)(pf + ((size_t)(t + 1) * RR + ridx[t]) * DD + d);
            s.x += g.x; s.y += g.y; s.z += g.z; s.w += g.w;
        }
        *(float4*)(featW + (size_t)r * DD + d) = s;
    }
}

// ---------------------------------------------------------------------------
// Heads phase B: K-split dot products. Block (rt, kc): 8 rows x K-chunk 256.
// part[kc][row][o] = feat[row][kc*256..+255] . Wt[o][same]
__global__ __launch_bounds__(256) void k_dots(const float* __restrict__ featW,
                                              const float* __restrict__ Wt,
                                              const int* __restrict__ ncompp,
                                              float* __restrict__ part) {
    int rt = blockIdx.x;               // 0..63
    int kc = blockIdx.y;               // 0..15
    int nc = *ncompp;
    int rbase = rt * RT;
    if (rbase >= nc) return;
    int nLive = min(RT, nc - rbase);

    __shared__ float fl[RT][KCS];      // 8 KB
    __shared__ float sc[RT][160];      // 5 KB (padded NHEAD)
    int tid = threadIdx.x;
#pragma unroll
    for (int rr = 0; rr < RT; ++rr)
        fl[rr][tid] = (rr < nLive) ? featW[(size_t)(rbase + rr) * DD + kc * KCS + tid] : 0.f;
    __syncthreads();

    int w = tid >> 6, lane = tid & 63;
    for (int o = w; o < NHEAD; o += 4) {
        float4 wv = *(const float4*)(Wt + (size_t)o * DD + kc * KCS + lane * 4);
        float s[RT];
#pragma unroll
        for (int rr = 0; rr < RT; ++rr) {
            float4 f = *(const float4*)&fl[rr][lane * 4];
            s[rr] = fmaf(wv.x, f.x, fmaf(wv.y, f.y, fmaf(wv.z, f.z, wv.w * f.w)));
        }
#pragma unroll
        for (int rr = 0; rr < RT; ++rr) {
            float v = s[rr];
            for (int off = 32; off; off >>= 1) v += __shfl_down(v, off);
            if (lane == 0) sc[rr][o] = v;
        }
    }
    __syncthreads();
    for (int i = tid; i < RT * NHEAD; i += 256) {
        int rr = i / NHEAD, o = i % NHEAD;
        if (rr < nLive)
            part[((size_t)kc * RR + rbase + rr) * 160 + o] = sc[rr][o];
    }
}

// ---------------------------------------------------------------------------
// Heads phase C: combine partials + bias, wave-parallel softmax, write out.
// Dead rows copy precomputed softmax(b_cls) + b_bbox (no expf).
__global__ __launch_bounds__(256) void k_finish(const float* __restrict__ part,
                                                const float* __restrict__ bc,
                                                const float* __restrict__ bbv,
                                                const float* __restrict__ dcls,
                                                const int* __restrict__ ncompp,
                                                const int* __restrict__ lblS,
                                                float* __restrict__ out) {
    int r = blockIdx.x, tid = threadIdx.x;
    float* cls = out;                                   // [NOUT][NCLS]
    float* bb  = out + (size_t)NOUT * NCLS;             // [NOUT][NBB]
    float* lb  = out + (size_t)NOUT * (NCLS + NBB);     // [NOUT]
    if (r >= *ncompp) {                                 // dead row: constants
        if (tid < NCLS) cls[(size_t)r * NCLS + tid] = dcls[tid];
        if (tid < NBB)  bb[(size_t)r * NBB + tid]   = bbv[tid];
        if (tid == 0)   lb[r] = 0.f;
        return;
    }
    __shared__ float scores[NHEAD];
    if (tid < NHEAD) {
        float s = (tid < NCLS) ? bc[tid] : bbv[tid - NCLS];
#pragma unroll
        for (int kc = 0; kc < KC_N; ++kc)
            s += part[((size_t)kc * RR + r) * 160 + tid];
        scores[tid] = s;
    }
    __syncthreads();
    if (tid < 64) {                                     // wave-parallel softmax
        float v = (tid < NCLS) ? scores[tid] : -3.4e38f;
        float mx = v;
        for (int m = 32; m; m >>= 1) mx = fmaxf(mx, __shfl_xor(mx, m));
        float e = (tid < NCLS) ? expf(v - mx) : 0.f;
        float sm = e;
        for (int m = 32; m; m >>= 1) sm += __shfl_xor(sm, m);
        if (tid < NCLS) cls[(size_t)r * NCLS + tid] = e / sm;
    }
    if (tid < NBB) bb[(size_t)r * NBB + tid] = scores[NCLS + tid];
    if (tid == 0)  lb[r] = (float)lblS[r];
}

// ---------------------------------------------------------------------------
// Fallback f32 path (ws too small): norms + VALU matcher + monolithic heads.
__global__ __launch_bounds__(256) void k_norms(const float* __restrict__ pf,
                                               float* __restrict__ norms) {
    int row = blockIdx.x;
    const float* p = pf + (size_t)row * DD;
    int tid = threadIdx.x;
    float s = 0.f;
    for (int d = tid * 4; d < DD; d += 1024) {
        float4 v = *(const float4*)(p + d);
        s = fmaf(v.x, v.x, s); s = fmaf(v.y, v.y, s);
        s = fmaf(v.z, v.z, s); s = fmaf(v.w, v.w, s);
    }
    for (int off = 32; off; off >>= 1) s += __shfl_down(s, off);
    __shared__ float wsum[4];
    if ((tid & 63) == 0) wsum[tid >> 6] = s;
    __syncthreads();
    if (tid == 0) norms[row] = wsum[0] + wsum[1] + wsum[2] + wsum[3];
}

__global__ __launch_bounds__(256) void k_match(const float* __restrict__ pf,
                                               const float* __restrict__ rois,
                                               const float* __restrict__ norms,
                                               unsigned long long* __restrict__ keys) {
    const int t  = blockIdx.z;
    const int ib = blockIdx.y * 64;
    const int jb = blockIdx.x * 64;
    const float* fa = pf + (size_t)t * RR * DD;
    const float* fb = pf + (size_t)(t + 1) * RR * DD;

    __shared__ float As[32][68];
    __shared__ float Bs[32][68];
    __shared__ float4 ra4[64];
    __shared__ float4 rb4[64];
    __shared__ unsigned long long red[16][64];

    const int tid = threadIdx.x;
    const int tx = tid & 15;
    const int ty = tid >> 4;

    if (tid < 64) {
        ra4[tid] = *(const float4*)(rois + ((size_t)t * RR + ib + tid) * 4);
        rb4[tid] = *(const float4*)(rois + ((size_t)(t + 1) * RR + jb + tid) * 4);
    }

    float acc[4][4];
#pragma unroll
    for (int u = 0; u < 4; ++u)
#pragma unroll
        for (int v = 0; v < 4; ++v) acc[u][v] = 0.f;

    const int lr = tid >> 3;
    const int lk = (tid & 7) * 4;

    for (int k0 = 0; k0 < DD; k0 += 32) {
        float4 a0 = *(const float4*)(fa + (size_t)(ib + lr) * DD + k0 + lk);
        float4 a1 = *(const float4*)(fa + (size_t)(ib + lr + 32) * DD + k0 + lk);
        float4 b0 = *(const float4*)(fb + (size_t)(jb + lr) * DD + k0 + lk);
        float4 b1 = *(const float4*)(fb + (size_t)(jb + lr + 32) * DD + k0 + lk);
        __syncthreads();
        As[lk + 0][lr] = a0.x; As[lk + 1][lr] = a0.y; As[lk + 2][lr] = a0.z; As[lk + 3][lr] = a0.w;
        As[lk + 0][lr + 32] = a1.x; As[lk + 1][lr + 32] = a1.y; As[lk + 2][lr + 32] = a1.z; As[lk + 3][lr + 32] = a1.w;
        Bs[lk + 0][lr] = b0.x; Bs[lk + 1][lr] = b0.y; Bs[lk + 2][lr] = b0.z; Bs[lk + 3][lr] = b0.w;
        Bs[lk + 0][lr + 32] = b1.x; Bs[lk + 1][lr + 32] = b1.y; Bs[lk + 2][lr + 32] = b1.z; Bs[lk + 3][lr + 32] = b1.w;
        __syncthreads();
#pragma unroll
        for (int kkk = 0; kkk < 32; ++kkk) {
            float4 av = *(const float4*)&As[kkk][ty * 4];
            float4 bv = *(const float4*)&Bs[kkk][tx * 4];
            float a_[4] = {av.x, av.y, av.z, av.w};
            float b_[4] = {bv.x, bv.y, bv.z, bv.w};
#pragma unroll
            for (int u = 0; u < 4; ++u)
#pragma unroll
                for (int v = 0; v < 4; ++v)
                    acc[u][v] = fmaf(a_[u], b_[v], acc[u][v]);
        }
    }
    __syncthreads();

    float na[4], nb_[4];
#pragma unroll
    for (int u = 0; u < 4; ++u) na[u]  = norms[t * RR + ib + ty * 4 + u];
#pragma unroll
    for (int v = 0; v < 4; ++v) nb_[v] = norms[(t + 1) * RR + jb + tx * 4 + v];

#pragma unroll
    for (int v = 0; v < 4; ++v) {
        unsigned long long bestkey = 0ull;
        float4 B = rb4[tx * 4 + v];
        float area_b = (B.z - B.x + 1.f) * (B.w - B.y + 1.f);
#pragma unroll
        for (int u = 0; u < 4; ++u) {
            float d2 = fmaxf(na[u] + nb_[v] - 2.f * acc[u][v], 0.f);
            float drev = 1.f / (1.f + sqrtf(d2));
            float4 A = ra4[ty * 4 + u];
            float area_a = (A.z - A.x + 1.f) * (A.w - A.y + 1.f);
            float iw = fmaxf(fminf(A.z, B.z) - fmaxf(A.x, B.x) + 1.f, 0.f);
            float ih = fmaxf(fminf(A.w, B.w) - fmaxf(A.y, B.y) + 1.f, 0.f);
            float inter = iw * ih;
            float iou = inter / (area_a + area_b - inter);
            float m = iou + drev;
            int gi = ib + ty * 4 + u;
            unsigned long long key =
                ((unsigned long long)__float_as_uint(m) << 32) |
                (unsigned long long)(unsigned)(RR - 1 - gi);
            if (key > bestkey) bestkey = key;
        }
        red[ty][tx * 4 + v] = bestkey;
    }
    __syncthreads();
    if (tid < 64) {
        unsigned long long best = red[0][tid];
#pragma unroll
        for (int r = 1; r < 16; ++r) {
            unsigned long long k = red[r][tid];
            if (k > best) best = k;
        }
        atomicMax(&keys[(size_t)t * RR + jb + tid], best);
    }
}

__global__ __launch_bounds__(256) void k_heads_fb(const float* __restrict__ pf,
                                                  const float* __restrict__ Wt,
                                                  const float* __restrict__ bc,
                                                  const float* __restrict__ bbias,
                                                  const int* __restrict__ src,
                                                  const int* __restrict__ lblS,
                                                  const int* __restrict__ ncompp,
                                                  const int* __restrict__ idx_all,
                                                  float* __restrict__ out) {
    __shared__ float feat[DD];
    __shared__ float scores[NHEAD];
    __shared__ int ridx[NPAIR];
    __shared__ float mx, sm;

    int r = blockIdx.x;
    int tid = threadIdx.x;
    int ncomp = *ncompp;
    bool comp = (r < ncomp);

    if (comp) {
        int j = src[r];
        if (tid < NPAIR) ridx[tid] = idx_all[tid * RR + j];
        __syncthreads();
        for (int d = tid * 4; d < DD; d += 1024) {
            float4 s = *(const float4*)(pf + (size_t)j * DD + d);
#pragma unroll
            for (int t = 0; t < NPAIR; ++t) {
                float4 g = *(const float4*)(pf + ((size_t)(t + 1) * RR + ridx[t]) * DD + d);
                s.x += g.x; s.y += g.y; s.z += g.z; s.w += g.w;
            }
            *(float4*)&feat[d] = s;
        }
        __syncthreads();
        int wid = tid >> 6, lane = tid & 63;
        for (int o = wid; o < NHEAD; o += 4) {
            const float* w = Wt + (size_t)o * DD;
            float s = 0.f;
            for (int d = lane * 4; d < DD; d += 256) {
                float4 wv = *(const float4*)(w + d);
                float4 fv = *(const float4*)&feat[d];
                s = fmaf(wv.x, fv.x, s); s = fmaf(wv.y, fv.y, s);
                s = fmaf(wv.z, fv.z, s); s = fmaf(wv.w, fv.w, s);
            }
            for (int off = 32; off; off >>= 1) s += __shfl_down(s, off);
            if (lane == 0) scores[o] = s + (o < NCLS ? bc[o] : bbias[o - NCLS]);
        }
        __syncthreads();
    } else {
        if (tid < NHEAD) scores[tid] = (tid < NCLS ? bc[tid] : bbias[tid - NCLS]);
        __syncthreads();
    }

    if (tid == 0) {
        float m = scores[0];
        for (int c = 1; c < NCLS; ++c) m = fmaxf(m, scores[c]);
        float s = 0.f;
        for (int c = 0; c < NCLS; ++c) s += expf(scores[c] - m);
        mx = m; sm = s;
    }
    __syncthreads();

    float* cls = out;
    float* bb  = out + (size_t)NOUT * NCLS;
    float* lb  = out + (size_t)NOUT * (NCLS + NBB);
    if (tid < NCLS) cls[(size_t)r * NCLS + tid] = expf(scores[tid] - mx) / sm;
    if (tid < NBB)  bb[(size_t)r * NBB + tid]   = scores[NCLS + tid];
    if (tid == 0)   lb[r] = comp ? (float)lblS[r] : 0.f;
}

// ---------------------------------------------------------------------------
extern "C" void kernel_launch(void* const* d_in, const int* in_sizes, int n_in,
                              void* d_out, int out_size, void* d_ws, size_t ws_size,
                              hipStream_t stream) {
    (void)in_sizes; (void)n_in; (void)out_size;
    const float* pf   = (const float*)d_in[0];
    const float* rois = (const float*)d_in[1];
    const int*   rlab = (const int*)d_in[2];
    const float* Wc   = (const float*)d_in[3];
    const float* bc   = (const float*)d_in[4];
    const float* Wb   = (const float*)d_in[5];
    const float* bbv  = (const float*)d_in[6];

    char* ws = (char*)d_ws;
    float*              norms   = (float*)(ws + OFF_NORMS);
    unsigned long long* keys    = (unsigned long long*)(ws + OFF_KEYS);
    int*                idx_all = (int*)(ws + OFF_IDX);
    int*                src     = (int*)(ws + OFF_SRC);
    int*                lblS    = (int*)(ws + OFF_LBL);
    int*                ncomp   = (int*)(ws + OFF_NCMP);
    float*              dcls    = (float*)(ws + OFF_DCLS);
    float*              Wt      = (float*)(ws + OFF_WT);
    unsigned short*     ph      = (unsigned short*)(ws + OFF_PH);
    unsigned short*     pl      = (unsigned short*)(ws + OFF_PL);
    float*              featW   = (float*)(ws + OFF_FEAT);
    float*              part    = (float*)(ws + OFF_PART);
    float*              out     = (float*)d_out;

    k_prep<<<dim3(2480), dim3(256), 0, stream>>>(keys, Wc, Wb, bc, Wt, dcls);
    if (ws_size >= (size_t)WS_NEED) {
        k_split<<<dim3(NOUT), dim3(256), 0, stream>>>(pf, ph, pl, norms);
        k_match_mfma<<<dim3(8, 8, NPAIR), dim3(256), 0, stream>>>(ph, pl, rois, norms, keys);
        k_finalize<<<dim3(1), dim3(512), 0, stream>>>(keys, rlab, idx_all, src, lblS, ncomp);
        k_gather<<<dim3(RR), dim3(256), 0, stream>>>(pf, src, ncomp, idx_all, featW);
        k_dots<<<dim3(RR / RT, KC_N), dim3(256), 0, stream>>>(featW, Wt, ncomp, part);
        k_finish<<<dim3(NOUT), dim3(256), 0, stream>>>(part, bc, bbv, dcls, ncomp, lblS, out);
    } else {
        k_norms<<<dim3(NOUT), dim3(256), 0, stream>>>(pf, norms);
        k_match<<<dim3(8, 8, NPAIR), dim3(256), 0, stream>>>(pf, rois, norms, keys);
        k_finalize<<<dim3(1), dim3(512), 0, stream>>>(keys, rlab, idx_all, src, lblS, ncomp);
        k_heads_fb<<<dim3(NOUT), dim3(256), 0, stream>>>(pf, Wt, bc, bbv, src, lblS, ncomp, idx_all, out);
    }
}